// Round 9
// baseline (139.618 us; speedup 1.0000x reference)
//
#include <hip/hip_runtime.h>

// Sinkhorn via separable kernel: K = exp(-C/eps) = G (x) G (kron), with
// G[a][b] = exp(-100 * C1d[a][b]) from exact 1D slices of the provided C
// (preserves reference's rounded dy^2). K.x = y-conv(G, x-conv(G, x)).
// Cost pass: K o C = H(x)G + G(x)H with H = G * C1d.
// R9 = measured-best R2 skeleton (12 waves x YB=4, two kernels, G/H in
// global -> compiler-proven wave-uniform s_load path; interleaved structure
// measured best across R3/R4/R6/R7/R8 variants) + register-resident
// per-wave state: ms/mt/fa/fb in 16 VGPRs (wave exclusively owns rows
// r0..r0+3) so step2 is LDS-read-free; all 12 src ds_read_b128 hoisted
// into one lgkmcnt batch; launch_bounds(768,1) frees VGPR cap (1 block/CU
// at 32 blocks, occupancy unaffected). G-in-LDS measured worse (R8);
// 16 waves worse (R4/R7); readlane worse (R6); pk-fma worse (R3).

#define SZ 48
#define SN 2304          // 48*48
#define LD 52            // padded LDS row stride (208 B, 16B-aligned)
#define NBAT 32
#define NTHR 768         // 12 waves
#define NW 12
#define YB 4             // output rows per wave (12*4 = 48)

__global__ __launch_bounds__(256) void k_pre(const float* __restrict__ C,
                                             float* __restrict__ G,
                                             float* __restrict__ H) {
    const int idx = blockIdx.x * 256 + threadIdx.x;   // 9*256 = 2304 exactly
    const int a = idx / SZ;
    const int c = idx - a * SZ;
    const float cv = C[(size_t)a * SZ * SN + (size_t)c * SZ];
    const float g = expf(-100.f * cv);
    G[idx] = g;
    H[idx] = g * cv;
}

__device__ __forceinline__ float getc(const float4 v, int i) {
    return i == 0 ? v.x : i == 1 ? v.y : i == 2 ? v.z : v.w;
}

// conv: out[k] = sum_j M[j][r0+k] * row[j], row read as 12 hoisted b128
__device__ __forceinline__ void conv4(const float* __restrict__ rowp,
                                      const float* __restrict__ Mm,
                                      int r0, float out[4]) {
    float4 q[12];
    #pragma unroll
    for (int jc = 0; jc < 12; ++jc)
        q[jc] = *(const float4*)&rowp[jc * 4];
    float a0 = 0.f, a1 = 0.f, a2 = 0.f, a3 = 0.f;
    #pragma unroll
    for (int jc = 0; jc < 12; ++jc) {
        #pragma unroll
        for (int jj = 0; jj < 4; ++jj) {
            const int j = jc * 4 + jj;
            const float4 g = *(const float4*)&Mm[j * SZ + r0];  // s_load (uniform)
            const float v = getc(q[jc], jj);
            a0 = fmaf(g.x, v, a0);
            a1 = fmaf(g.y, v, a1);
            a2 = fmaf(g.z, v, a2);
            a3 = fmaf(g.w, v, a3);
        }
    }
    out[0] = a0; out[1] = a1; out[2] = a2; out[3] = a3;
}

__global__ __launch_bounds__(NTHR, 1) void k_sink(const float* __restrict__ pred,
                                                  const float* __restrict__ tgt,
                                                  const float* __restrict__ Gm,
                                                  const float* __restrict__ Hm,
                                                  float* __restrict__ out) {
    __shared__ float FaL[SZ * LD];   // alpha plane (master copy for step1)
    __shared__ float FbL[SZ * LD];   // beta plane
    __shared__ float FmsL[SZ * LD];  // init staging; T2t plane in final
    __shared__ float FmtL[SZ * LD];  // init staging
    __shared__ float Tt[SZ * LD];    // conv intermediate, TRANSPOSED [xi][y]
    __shared__ float gsl[SZ];        // row sums of G (folded pass 0)
    __shared__ float red[32];

    const int t = threadIdx.x;
    const int b = blockIdx.x;
    const int l = t & 63;
    const int w = __builtin_amdgcn_readfirstlane(t >> 6);  // scalar wave id
    const int r0 = w * YB;                                 // wave's rows
    const int lc = (l < SZ) ? l : 0;

    // ---- init: vectorized plane loads + block sums; gsl row sums ----
    if (t < SZ) {
        float s = 0.f;
        #pragma unroll 8
        for (int j = 0; j < SZ; ++j) s += Gm[t * SZ + j];
        gsl[t] = s;
    }
    const float4* __restrict__ pg4 =
        (const float4*)(pred + (size_t)b * 3 * SN);
    const float4* __restrict__ tg4 =
        (const float4*)(tgt + (size_t)b * 3 * SN);
    float sp = 0.f, st = 0.f;
    if (t < 576) {                       // 576 float4 = 2304 floats
        const int y = t / 12, xc = (t - y * 12) * 4;
        float4 vp = pg4[t], vt = tg4[t];
        vp.x += 1e-9f; vp.y += 1e-9f; vp.z += 1e-9f; vp.w += 1e-9f;
        vt.x += 1e-9f; vt.y += 1e-9f; vt.z += 1e-9f; vt.w += 1e-9f;
        *(float4*)&FmsL[y * LD + xc] = vp;
        *(float4*)&FmtL[y * LD + xc] = vt;
        sp = vp.x + vp.y + vp.z + vp.w;
        st = vt.x + vt.y + vt.z + vt.w;
    }
    #pragma unroll
    for (int off = 32; off; off >>= 1) {
        sp += __shfl_down(sp, off);
        st += __shfl_down(st, off);
    }
    if (l == 0) { red[w] = sp; red[16 + w] = st; }
    __syncthreads();
    float ps = 0.f, ts = 0.f;
    #pragma unroll
    for (int k = 0; k < NW; ++k) { ps += red[k]; ts += red[16 + k]; }

    // ---- register state + folded pass 0 ----
    // wave w exclusively owns rows r0..r0+3; thread = (row k, col l)
    float ms[4], mt[4], fa[4], fb[4];
    {
        const float gx = gsl[lc];
        #pragma unroll
        for (int k = 0; k < YB; ++k) {
            ms[k] = FmsL[(r0 + k) * LD + lc] / ps;
            mt[k] = FmtL[(r0 + k) * LD + lc] / ts;
            fa[k] = ms[k] / (gsl[r0 + k] * gx + 1e-6f);
            fb[k] = 1.f;
        }
        if (l < SZ) {
            #pragma unroll
            for (int k = 0; k < YB; ++k) {
                FaL[(r0 + k) * LD + l] = fa[k];
                FbL[(r0 + k) * LD + l] = 1.f;
            }
        }
    }
    __syncthreads();

    // ---- 9 half-iterations: odd p (5x: Fa->Fb), even p (4x: Fb->Fa) ----
    #pragma unroll 1
    for (int p = 1; p < 10; ++p) {
        const float* __restrict__ srcp = (p & 1) ? FaL : FbL;
        float* __restrict__ dstp       = (p & 1) ? FbL : FaL;
        float* dreg                    = (p & 1) ? fb : fa;
        const float* mvr               = (p & 1) ? mt : ms;

        // step1 (x-conv): Tt[xi][y] = sum_j G[xi][j] * src[y][j]
        float s4[4];
        conv4(&srcp[lc * LD], Gm, r0, s4);
        if (l < SZ) {
            Tt[(r0 + 0) * LD + l] = s4[0];   // lane-contiguous, conflict-free
            Tt[(r0 + 1) * LD + l] = s4[1];
            Tt[(r0 + 2) * LD + l] = s4[2];
            Tt[(r0 + 3) * LD + l] = s4[3];
        }
        __syncthreads();

        // step2 (y-conv) + register update: S[yi][x] = sum_j G[yi][j]*Tt[x][j]
        conv4(&Tt[lc * LD], Gm, r0, s4);
        #pragma unroll
        for (int k = 0; k < YB; ++k) {
            const float yo = dreg[k];
            dreg[k] = mvr[k] * yo / (yo * s4[k] + 1e-6f);
        }
        if (l < SZ) {
            #pragma unroll
            for (int k = 0; k < YB; ++k)
                dstp[(r0 + k) * LD + l] = dreg[k];
        }
        __syncthreads();
    }

    // ---- final: cost = sum Fa .* ((H(x)G + G(x)H) applied to Fb) ----
    // stage 1: T1t = (G-x-conv(Fb))^T -> Tt, T2t = (H-x-conv(Fb))^T -> FmsL
    {
        float4 q[12];
        #pragma unroll
        for (int jc = 0; jc < 12; ++jc)
            q[jc] = *(const float4*)&FbL[lc * LD + jc * 4];
        float t1[4] = {0.f, 0.f, 0.f, 0.f}, t2[4] = {0.f, 0.f, 0.f, 0.f};
        #pragma unroll
        for (int jc = 0; jc < 12; ++jc) {
            #pragma unroll
            for (int jj = 0; jj < 4; ++jj) {
                const int j = jc * 4 + jj;
                const float4 g = *(const float4*)&Gm[j * SZ + r0];
                const float4 h = *(const float4*)&Hm[j * SZ + r0];
                const float v = getc(q[jc], jj);
                t1[0] = fmaf(g.x, v, t1[0]);  t1[1] = fmaf(g.y, v, t1[1]);
                t1[2] = fmaf(g.z, v, t1[2]);  t1[3] = fmaf(g.w, v, t1[3]);
                t2[0] = fmaf(h.x, v, t2[0]);  t2[1] = fmaf(h.y, v, t2[1]);
                t2[2] = fmaf(h.z, v, t2[2]);  t2[3] = fmaf(h.w, v, t2[3]);
            }
        }
        if (l < SZ) {
            #pragma unroll
            for (int k = 0; k < YB; ++k) {
                Tt  [(r0 + k) * LD + l] = t1[k];
                FmsL[(r0 + k) * LD + l] = t2[k];
            }
        }
    }
    __syncthreads();

    // stage 2: U[yi][x] = sum_j H[yi][j]*T1t[x][j] + G[yi][j]*T2t[x][j]
    float part = 0.f;
    {
        float4 q1[12], q2[12];
        #pragma unroll
        for (int jc = 0; jc < 12; ++jc) {
            q1[jc] = *(const float4*)&Tt  [lc * LD + jc * 4];
            q2[jc] = *(const float4*)&FmsL[lc * LD + jc * 4];
        }
        float u[4] = {0.f, 0.f, 0.f, 0.f};
        #pragma unroll
        for (int jc = 0; jc < 12; ++jc) {
            #pragma unroll
            for (int jj = 0; jj < 4; ++jj) {
                const int j = jc * 4 + jj;
                const float4 g = *(const float4*)&Gm[j * SZ + r0];
                const float4 h = *(const float4*)&Hm[j * SZ + r0];
                const float v1 = getc(q1[jc], jj);
                const float v2 = getc(q2[jc], jj);
                u[0] = fmaf(h.x, v1, u[0]);  u[1] = fmaf(h.y, v1, u[1]);
                u[2] = fmaf(h.z, v1, u[2]);  u[3] = fmaf(h.w, v1, u[3]);
                u[0] = fmaf(g.x, v2, u[0]);  u[1] = fmaf(g.y, v2, u[1]);
                u[2] = fmaf(g.z, v2, u[2]);  u[3] = fmaf(g.w, v2, u[3]);
            }
        }
        if (l < SZ) {
            #pragma unroll
            for (int k = 0; k < YB; ++k)
                part = fmaf(fa[k], u[k], part);
        }
    }
    #pragma unroll
    for (int off = 32; off; off >>= 1) part += __shfl_down(part, off);
    if (l == 0) red[w] = part;
    __syncthreads();
    if (t == 0) {
        float c = 0.f;
        #pragma unroll
        for (int k = 0; k < NW; ++k) c += red[k];
        out[b] = c;
    }
}

extern "C" void kernel_launch(void* const* d_in, const int* in_sizes, int n_in,
                              void* d_out, int out_size, void* d_ws, size_t ws_size,
                              hipStream_t stream) {
    const float* pred = (const float*)d_in[0];
    const float* tgt  = (const float*)d_in[1];
    const float* C    = (const float*)d_in[2];
    float* G = (float*)d_ws;          // 2304 floats
    float* H = G + SN;                // 2304 floats

    k_pre<<<9, 256, 0, stream>>>(C, G, H);
    k_sink<<<NBAT, NTHR, 0, stream>>>(pred, tgt, G, H, (float*)d_out);
}

// Round 10
// 102.623 us; speedup vs baseline: 1.3605x; 1.3605x over previous
//
#include <hip/hip_runtime.h>

// Sinkhorn via separable kernel: K = exp(-C/eps) = G (x) G (kron), with
// G[a][b] = exp(-100 * C1d[a][b]) read as exact 1D slices of the provided C
// (preserves reference's rounded dy^2). K.x = y-conv(G, x-conv(G, x)).
// Cost pass: K o C = H(x)G + G(x)H with H = G * C1d.
// One block per batch (32 blocks), whole chain in one kernel, state in LDS
// ([48][49] padded rows: row- and column-direction b32 accesses are at
// worst 2-way bank aliased = free). 12 waves x 4 rows; folded pass 0
// (beta==1 -> S0 = gs[y]*gs[x]); k_pre spread over 9 blocks.
// R10 = byte-exact restore of the session-best kernel (measured 101.88 us
// total). All 8 structural variants measured worse: float4 LDS reads +
// pk-fma (R3), hoisted loads + 16 waves (R4), readlane register state (R6),
// 16-wave interleaved (R7), G-in-LDS (R8), reg-state + hoisted b128 (R9).
// Scalar interleaved conflict-free LDS reads + wave-uniform global G
// (compiler s_load path) + 12 waves is the measured optimum.

#define SZ 48
#define SN 2304          // 48*48
#define LD 49            // padded LDS row stride
#define NBAT 32
#define NTHR 768         // 12 waves
#define NW 12
#define YB 4             // output rows per wave (12*4 = 48)

__global__ __launch_bounds__(256) void k_pre(const float* __restrict__ C,
                                             float* __restrict__ G,
                                             float* __restrict__ H) {
    const int idx = blockIdx.x * 256 + threadIdx.x;   // 9*256 = 2304 exactly
    const int a = idx / SZ;
    const int c = idx - a * SZ;
    const float cv = C[(size_t)a * SZ * SN + (size_t)c * SZ];
    const float g = expf(-100.f * cv);
    G[idx] = g;
    H[idx] = g * cv;
}

__global__ __launch_bounds__(NTHR) void k_sink(const float* __restrict__ pred,
                                               const float* __restrict__ tgt,
                                               const float* __restrict__ Gm,
                                               const float* __restrict__ Hm,
                                               float* __restrict__ out) {
    __shared__ float Fa[SZ * LD];    // alpha scaling
    __shared__ float Fb[SZ * LD];    // beta scaling (init 1)
    __shared__ float Fms[SZ * LD];   // mass_source; reused as T2 in final
    __shared__ float Fmt[SZ * LD];   // mass_target
    __shared__ float T[SZ * LD];     // conv intermediate
    __shared__ float gsl[SZ];        // row sums of G (for folded pass 0)
    __shared__ float red[32];

    const int t = threadIdx.x;
    const int b = blockIdx.x;
    const int l = t & 63;
    const int w = __builtin_amdgcn_readfirstlane(t >> 6);  // scalar wave id
    const int r0 = w * YB;                                 // wave's output rows

    // ---- init: G row sums, load channel-0 planes, sum, normalize ----
    if (t < SZ) {
        float s = 0.f;
        #pragma unroll 8
        for (int j = 0; j < SZ; ++j) s += Gm[t * SZ + j];
        gsl[t] = s;
    }
    const float* __restrict__ pg = pred + (size_t)b * 3 * SN;
    const float* __restrict__ tg = tgt + (size_t)b * 3 * SN;
    float sp = 0.f, st = 0.f;
    for (int i = t; i < SN; i += NTHR) {
        const float vp = pg[i] + 1e-9f;
        const float vt = tg[i] + 1e-9f;
        const int y = i / SZ, x = i - y * SZ;
        Fms[y * LD + x] = vp;
        Fmt[y * LD + x] = vt;
        sp += vp; st += vt;
    }
    #pragma unroll
    for (int off = 32; off; off >>= 1) {
        sp += __shfl_down(sp, off);
        st += __shfl_down(st, off);
    }
    if (l == 0) { red[w] = sp; red[16 + w] = st; }
    __syncthreads();
    float ps = 0.f, ts = 0.f;
    #pragma unroll
    for (int k = 0; k < NW; ++k) { ps += red[k]; ts += red[16 + k]; }
    // folded pass 0: Fa = m_src / (gs[y]*gs[x] + 1e-6), Fb = 1
    for (int i = t; i < SN; i += NTHR) {
        const int y = i / SZ, x = i - y * SZ;
        const float ms = Fms[y * LD + x] / ps;
        Fms[y * LD + x] = ms;
        Fmt[y * LD + x] /= ts;
        Fa[y * LD + x] = ms / (gsl[y] * gsl[x] + 1e-6f);
        Fb[y * LD + x] = 1.f;
    }
    __syncthreads();

    // ---- remaining 9 half-iterations (p=1..9) ----
    for (int p = 1; p < 10; ++p) {
        float* __restrict__ src = (p & 1) ? Fa : Fb;
        float* __restrict__ dst = (p & 1) ? Fb : Fa;
        const float* __restrict__ mv = (p & 1) ? Fmt : Fms;

        // step1 (x-conv): T[y][xi] = sum_j G[xi][j] * src[y][j]
        if (l < SZ) {
            float acc[YB];
            #pragma unroll
            for (int k = 0; k < YB; ++k) acc[k] = 0.f;
            #pragma unroll 8
            for (int j = 0; j < SZ; ++j) {
                const float v = src[l * LD + j];            // 2-way max = free
                #pragma unroll
                for (int k = 0; k < YB; ++k)
                    acc[k] = fmaf(Gm[j * SZ + r0 + k], v, acc[k]);  // s_load_dwordx4
            }
            #pragma unroll
            for (int k = 0; k < YB; ++k) T[l * LD + r0 + k] = acc[k];
        }
        __syncthreads();

        // step2 (y-conv) + fused scaling update:
        // S[yi][x] = sum_j G[yi][j]*T[j][x]; dst = mv*dst/(dst*S + 1e-6)
        if (l < SZ) {
            float acc[YB];
            #pragma unroll
            for (int k = 0; k < YB; ++k) acc[k] = 0.f;
            #pragma unroll 8
            for (int j = 0; j < SZ; ++j) {
                const float v = T[j * LD + l];              // conflict-free
                #pragma unroll
                for (int k = 0; k < YB; ++k)
                    acc[k] = fmaf(Gm[j * SZ + r0 + k], v, acc[k]);
            }
            #pragma unroll
            for (int k = 0; k < YB; ++k) {
                const int idx = (r0 + k) * LD + l;
                const float yo = dst[idx];
                dst[idx] = mv[idx] * yo / (yo * acc[k] + 1e-6f);
            }
        }
        __syncthreads();
    }

    // ---- final: cost = sum Fa .* ((H(x)G + G(x)H) applied to Fb) ----
    // stage 1: T1 = G-x-conv(beta) -> T, T2 = H-x-conv(beta) -> Fms
    if (l < SZ) {
        float t1[YB], t2[YB];
        #pragma unroll
        for (int k = 0; k < YB; ++k) { t1[k] = 0.f; t2[k] = 0.f; }
        #pragma unroll 4
        for (int j = 0; j < SZ; ++j) {
            const float v = Fb[l * LD + j];
            #pragma unroll
            for (int k = 0; k < YB; ++k) {
                t1[k] = fmaf(Gm[j * SZ + r0 + k], v, t1[k]);
                t2[k] = fmaf(Hm[j * SZ + r0 + k], v, t2[k]);
            }
        }
        #pragma unroll
        for (int k = 0; k < YB; ++k) {
            T  [l * LD + r0 + k] = t1[k];
            Fms[l * LD + r0 + k] = t2[k];
        }
    }
    __syncthreads();

    // stage 2: U[yi][x] = sum_j H[yi][j]*T1[j][x] + G[yi][j]*T2[j][x]
    float part = 0.f;
    if (l < SZ) {
        float u[YB];
        #pragma unroll
        for (int k = 0; k < YB; ++k) u[k] = 0.f;
        #pragma unroll 4
        for (int j = 0; j < SZ; ++j) {
            const float v1 = T  [j * LD + l];
            const float v2 = Fms[j * LD + l];
            #pragma unroll
            for (int k = 0; k < YB; ++k) {
                u[k] = fmaf(Hm[j * SZ + r0 + k], v1, u[k]);
                u[k] = fmaf(Gm[j * SZ + r0 + k], v2, u[k]);
            }
        }
        #pragma unroll
        for (int k = 0; k < YB; ++k)
            part = fmaf(Fa[(r0 + k) * LD + l], u[k], part);
    }
    #pragma unroll
    for (int off = 32; off; off >>= 1) part += __shfl_down(part, off);
    if (l == 0) red[w] = part;
    __syncthreads();
    if (t == 0) {
        float c = 0.f;
        #pragma unroll
        for (int k = 0; k < NW; ++k) c += red[k];
        out[b] = c;
    }
}

extern "C" void kernel_launch(void* const* d_in, const int* in_sizes, int n_in,
                              void* d_out, int out_size, void* d_ws, size_t ws_size,
                              hipStream_t stream) {
    const float* pred = (const float*)d_in[0];
    const float* tgt  = (const float*)d_in[1];
    const float* C    = (const float*)d_in[2];
    float* G = (float*)d_ws;          // 2304 floats
    float* H = G + SN;                // 2304 floats

    k_pre<<<9, 256, 0, stream>>>(C, G, H);
    k_sink<<<NBAT, NTHR, 0, stream>>>(pred, tgt, G, H, (float*)d_out);
}